// Round 7
// baseline (273.306 us; speedup 1.0000x reference)
//
#include <hip/hip_runtime.h>
#include <hip/hip_bf16.h>
#include <cstdint>

// ---------------------------------------------------------------------------
// AttentionModel: out = softmax((xWq^T+bq)(xWk^T+bk)^T / 32) (xWv^T+bv)
// B=4, S=2048, E=1024, fp32 in/out.  bf16 MFMA pipeline.
// R7: PV GEMM was occupancy-starved (512 blocks = 2 blocks/CU vs the 4 the
// register budget allows). Split-K=2: grid.z = batch(4) x khalf(2) = 8 ->
// 1024 blocks, 4/CU. Partial outputs combined via fp32 atomicAdd after the
// 1/rowsum scaling (commutes with the K-split sum). d_out zeroed inside
// convert_all (harness poisons it 0xAA before every launch).
// Core (R3/R5/R6-proven): 16x16x32 MFMA, BK=64, XOR granule swizzle (0 LDS
// conflicts), __launch_bounds__(256,4) -> 64 VGPR + 64 AGPR = 4 blocks/CU.
// ---------------------------------------------------------------------------

typedef __attribute__((ext_vector_type(8))) short bf16x8;
typedef __attribute__((ext_vector_type(4))) float f32x4;

__device__ __forceinline__ unsigned short f2bf(float f) {
  union { float f; uint32_t u; } x; x.f = f;
  uint32_t u = x.u;
  return (unsigned short)((u + 0x7fffu + ((u >> 16) & 1u)) >> 16);  // RNE
}

__device__ __forceinline__ void async_copy16(const void* g, void* l) {
  __builtin_amdgcn_global_load_lds(
      (const __attribute__((address_space(1))) void*)g,
      (__attribute__((address_space(3))) void*)l, 16, 0, 0);
}

// ---------------------------------------------------------------------------
// Merged fp32->bf16 convert for x, Wq, Wk, Wv; also zeroes rowsum and d_out.
// Grid: [0, CONV) convert | [CONV, CONV+2048) zero d_out | last: zero rowsum
// ---------------------------------------------------------------------------
#define CONV_BLOCKS 11264  // (8192*1024/4 + 3*1024*1024/4) / 256
__global__ __launch_bounds__(256) void convert_all(
    const float* __restrict__ x, const float* __restrict__ Wq,
    const float* __restrict__ Wk, const float* __restrict__ Wv,
    unsigned short* __restrict__ xb, unsigned short* __restrict__ Wb,
    float* __restrict__ rowsum, float* __restrict__ outz) {
  const long X4 = (long)8192 * 1024 / 4;
  const long W4 = (long)1024 * 1024 / 4;
  const int bid = blockIdx.x;
  if (bid >= CONV_BLOCKS) {
    if (bid == gridDim.x - 1) {
      // zero 8192 fp32 rowsums
      float4* r = (float4*)rowsum;
#pragma unroll
      for (int t = 0; t < 8; ++t)
        r[threadIdx.x + t * 256] = float4{0.f, 0.f, 0.f, 0.f};
    } else {
      // zero d_out: 2048 blocks x 256 threads x 4 float4 = 8192*1024 floats
      float4* o = (float4*)outz + (long)(bid - CONV_BLOCKS) * 1024;
#pragma unroll
      for (int t = 0; t < 4; ++t)
        o[threadIdx.x + t * 256] = float4{0.f, 0.f, 0.f, 0.f};
    }
    return;
  }
  long i = (long)bid * 256 + threadIdx.x;
  const float* src; unsigned short* dst; long off;
  if (i < X4)             { src = x;  dst = xb;                    off = i; }
  else if (i < X4 + W4)   { src = Wq; dst = Wb;                    off = i - X4; }
  else if (i < X4 + 2*W4) { src = Wk; dst = Wb + (long)1024*1024;  off = i - X4 - W4; }
  else                    { src = Wv; dst = Wb + (long)2048*1024;  off = i - X4 - 2*W4; }
  const float4 v = ((const float4*)src)[off];
  ushort4 o;
  o.x = f2bf(v.x); o.y = f2bf(v.y); o.z = f2bf(v.z); o.w = f2bf(v.w);
  ((ushort4*)dst)[off] = o;
}

// ---------------------------------------------------------------------------
// C[M,N] = op( scale * (A[M,K] x B[N,K]^T) + bias )
// MODE 0 (PROJ):   bf16 out; z<2 -> normal rows; z==2 -> write V transposed
// MODE 1 (SCORES): bf16 out = exp(scale*acc); atomicAdd per-row sums
// MODE 2 (PV):     split-K: z = khalf*4 + batch; fp32 atomicAdd of
//                  acc * (1/rowsum[row]) into pre-zeroed d_out
// 256 threads = 4 waves, 128x128 tile, BK=64, 16x16x32 bf16 MFMA.
// ldAB = row stride of A and B (== full K even when loop K is a split half).
// ---------------------------------------------------------------------------
template <int MODE>
__global__ __launch_bounds__(256, 4) void gemm_bt(
    const unsigned short* __restrict__ Ab, const unsigned short* __restrict__ Bb,
    unsigned short* __restrict__ Cb, float* __restrict__ Cf,
    unsigned short* __restrict__ VT,
    const float* __restrict__ bias0, const float* __restrict__ bias1,
    const float* __restrict__ bias2, float* __restrict__ rowsum,
    int K, int N, float scale, long sA, long sB, long sC, long ldAB) {
  __shared__ unsigned short As[128 * 64];
  __shared__ unsigned short Bs[128 * 64];

  int z = blockIdx.z;
  long koff = 0;
  if (MODE == 2) { koff = (long)(z >> 2) * K; z &= 3; }
  const unsigned short* A  = Ab + (long)z * sA + koff;
  const unsigned short* Bm = Bb + (long)z * sB + koff;

  const int tid  = threadIdx.x;
  const int lane = tid & 63;
  const int wave = tid >> 6;
  const int l15  = lane & 15;
  const int quad = lane >> 4;
  const int wm = (wave >> 1) * 64;
  const int wn = (wave & 1) * 64;

  const int tile_m = blockIdx.x * 128;
  const int tile_n = blockIdx.y * 128;

  // --- staging map: wave w covers rows [w*32, w*32+32), 4 instrs x 8 rows.
  // Lane L -> LDS slot L&7 of row strip+(L>>3); content = chunk (L&7)^(L>>3).
  const int rs8 = lane >> 3;
  const int kc  = (lane & 7) ^ rs8;
  const long lK = ldAB;
  const unsigned short* gA0 = A  + (long)(tile_m + wave * 32 + rs8) * lK + kc * 8;
  const unsigned short* gB0 = Bm + (long)(tile_n + wave * 32 + rs8) * lK + kc * 8;
  unsigned short* lA = &As[(wave * 32) * 64];
  unsigned short* lB = &Bs[(wave * 32) * 64];

  // --- fragment granule select: physical = (s*4+quad) ^ (row&7), row&7=l15&7
  const int g0 = (0 * 4 + quad) ^ (l15 & 7);
  const int g1 = (1 * 4 + quad) ^ (l15 & 7);

  f32x4 acc[4][4] = {};

  for (int k0 = 0; k0 < K; k0 += 64) {
    __syncthreads();  // previous-iter LDS readers done
#pragma unroll
    for (int t = 0; t < 4; ++t) {
      async_copy16(gA0 + (long)t * 8 * lK + k0, lA + t * 8 * 64);
      async_copy16(gB0 + (long)t * 8 * lK + k0, lB + t * 8 * 64);
    }
    __syncthreads();  // drain: LDS tile ready

#pragma unroll
    for (int s = 0; s < 2; ++s) {
      const int gs = s ? g1 : g0;
      bf16x8 af[4], bfr[4];
#pragma unroll
      for (int i = 0; i < 4; ++i)
        af[i] = *(const bf16x8*)&As[(wm + i * 16 + l15) * 64 + gs * 8];
#pragma unroll
      for (int j = 0; j < 4; ++j)
        bfr[j] = *(const bf16x8*)&Bs[(wn + j * 16 + l15) * 64 + gs * 8];
#pragma unroll
      for (int i = 0; i < 4; ++i)
#pragma unroll
        for (int j = 0; j < 4; ++j)
          acc[i][j] = __builtin_amdgcn_mfma_f32_16x16x32_bf16(af[i], bfr[j], acc[i][j], 0, 0, 0);
    }
  }

  // ------------------------- epilogue -------------------------
  // C/D layout: col = lane&15, row = quad*4 + reg (m89-verified)
  if (MODE == 0) {
    const float* bias = (z == 0) ? bias0 : (z == 1) ? bias1 : bias2;
    if (z == 2) {
      // write V transposed: VT[b][f][s], b = row>>11, s = row&2047
#pragma unroll
      for (int j = 0; j < 4; ++j) {
        const int col = tile_n + wn + j * 16 + l15;  // feature f
        const float bv = bias[col];
#pragma unroll
        for (int i = 0; i < 4; ++i) {
          const int row0 = tile_m + wm + i * 16 + quad * 4;  // token
          const int b = row0 >> 11;
          const int sx = row0 & 2047;
          ushort4 o;
          o.x = f2bf(acc[i][j][0] + bv);
          o.y = f2bf(acc[i][j][1] + bv);
          o.z = f2bf(acc[i][j][2] + bv);
          o.w = f2bf(acc[i][j][3] + bv);
          *(ushort4*)&VT[(long)b * 1024 * 2048 + (long)col * 2048 + sx] = o;
        }
      }
    } else {
      unsigned short* Cbz = Cb + (long)z * sC;
#pragma unroll
      for (int j = 0; j < 4; ++j) {
        const int col = tile_n + wn + j * 16 + l15;
        const float bv = bias[col];
#pragma unroll
        for (int i = 0; i < 4; ++i) {
          const int row0 = tile_m + wm + i * 16 + quad * 4;
#pragma unroll
          for (int r = 0; r < 4; ++r)
            Cbz[(long)(row0 + r) * N + col] = f2bf(acc[i][j][r] + bv);
        }
      }
    }
  } else if (MODE == 1) {
    // exp epilogue + row-sum atomics
    unsigned short* Cbz = Cb + (long)z * sC;
    float part[16];
#pragma unroll
    for (int t = 0; t < 16; ++t) part[t] = 0.0f;
#pragma unroll
    for (int j = 0; j < 4; ++j) {
      const int col = tile_n + wn + j * 16 + l15;
#pragma unroll
      for (int i = 0; i < 4; ++i) {
        const int row0 = tile_m + wm + i * 16 + quad * 4;
#pragma unroll
        for (int r = 0; r < 4; ++r) {
          const float e = __expf(acc[i][j][r] * scale);
          part[i * 4 + r] += e;
          Cbz[(long)(row0 + r) * N + col] = f2bf(e);
        }
      }
    }
    // reduce across the 16 lanes (l15) sharing each row
#pragma unroll
    for (int t = 0; t < 16; ++t)
#pragma unroll
      for (int o = 1; o < 16; o <<= 1)
        part[t] += __shfl_xor(part[t], o);
    if (l15 == 0) {
#pragma unroll
      for (int i = 0; i < 4; ++i) {
        const int row0 = tile_m + wm + i * 16 + quad * 4;
#pragma unroll
        for (int r = 0; r < 4; ++r)
          atomicAdd(&rowsum[z * 2048 + row0 + r], part[i * 4 + r]);
      }
    }
  } else {
    // PV split-K: atomic-accumulate normalized partials into zeroed d_out
    float* Cfz = Cf + (long)z * sC;
    float inv[16];
#pragma unroll
    for (int i = 0; i < 4; ++i) {
      const int row0 = tile_m + wm + i * 16 + quad * 4;
#pragma unroll
      for (int r = 0; r < 4; ++r)
        inv[i * 4 + r] = 1.0f / rowsum[z * 2048 + row0 + r];
    }
#pragma unroll
    for (int j = 0; j < 4; ++j) {
      const int col = tile_n + wn + j * 16 + l15;
#pragma unroll
      for (int i = 0; i < 4; ++i) {
        const int row0 = tile_m + wm + i * 16 + quad * 4;
#pragma unroll
        for (int r = 0; r < 4; ++r)
          atomicAdd(&Cfz[(long)(row0 + r) * N + col],
                    acc[i][j][r] * inv[i * 4 + r]);
      }
    }
  }
}

// ---------------------------------------------------------------------------
extern "C" void kernel_launch(void* const* d_in, const int* in_sizes, int n_in,
                              void* d_out, int out_size, void* d_ws, size_t ws_size,
                              hipStream_t stream) {
  const float* x  = (const float*)d_in[0];
  const float* Wq = (const float*)d_in[1];
  const float* bq = (const float*)d_in[2];
  const float* Wk = (const float*)d_in[3];
  const float* bk = (const float*)d_in[4];
  const float* Wv = (const float*)d_in[5];
  const float* bv = (const float*)d_in[6];
  float* out = (float*)d_out;

  constexpr int Bt = 4, S = 2048, E = 1024;
  constexpr int M = Bt * S;  // 8192

  // ws layout (bf16): x_bf | W_bf(3) | Q | K | VT | P(exp scores) | rowsum(f32)
  unsigned short* xb = (unsigned short*)d_ws;
  unsigned short* Wb = xb + (size_t)M * E;
  unsigned short* Q  = Wb + (size_t)3 * E * E;
  unsigned short* Kb = Q + (size_t)M * E;
  unsigned short* VT = Kb + (size_t)M * E;
  unsigned short* P  = VT + (size_t)M * E;
  float* rowsum = (float*)(P + (size_t)Bt * S * S);

  // 1) converts + rowsum/d_out zeroing (one launch)
  convert_all<<<dim3(CONV_BLOCKS + 2048 + 1), dim3(256), 0, stream>>>(
      x, Wq, Wk, Wv, xb, Wb, rowsum, out);

  // 2) projections: z in {Q,K,V}; y = x W^T + b; V written transposed
  gemm_bt<0><<<dim3(M / 128, E / 128, 3), dim3(256), 0, stream>>>(
      xb, Wb, Q, nullptr, VT, bq, bk, bv, nullptr, E, E, 1.0f,
      0L, (long)E * E, (long)M * E, (long)E);

  // 3) P = exp(Q K^T / 32) (unnormalized) + row sums
  gemm_bt<1><<<dim3(S / 128, S / 128, Bt), dim3(256), 0, stream>>>(
      Q, Kb, P, nullptr, nullptr, nullptr, nullptr, nullptr, rowsum,
      E, S, 1.0f / 32.0f, (long)S * E, (long)S * E, (long)S * S, (long)E);

  // 4) out += (P[:, half] V[half, :]) / rowsum  — split-K=2, z = half*4+b
  gemm_bt<2><<<dim3(S / 128, E / 128, 2 * Bt), dim3(256), 0, stream>>>(
      P, VT, nullptr, out, nullptr, nullptr, nullptr, nullptr, rowsum,
      S / 2, E, 1.0f, (long)S * S, (long)E * S, (long)S * E, (long)S);
}

// Round 8
// 230.397 us; speedup vs baseline: 1.1862x; 1.1862x over previous
//
#include <hip/hip_runtime.h>
#include <hip/hip_bf16.h>
#include <cstdint>

// ---------------------------------------------------------------------------
// AttentionModel: out = softmax((xWq^T+bq)(xWk^T+bk)^T / 32) (xWv^T+bv)
// B=4, S=2048, E=1024, fp32 in/out.  bf16 MFMA pipeline.
// R8: revert R7's split-K (global-atomic epilogue cost >> occupancy gain;
// PV MfmaUtil fell to 16%). Back to R6 core + 8x8 super-tile block swizzle:
// co-resident blocks share 8 A-tiles + 8 B-tiles (~4 MB) instead of the
// whole matrix -> better L2 hit on staging (scores FETCH was 82 MB vs
// proj 44 MB; scores/PV at 594 TF vs proj 888 TF = m97-structure plateau).
// Core (R3/R5/R6-proven): 16x16x32 MFMA, BK=64, XOR granule swizzle (0 LDS
// conflicts), __launch_bounds__(256,4) -> 64 VGPR + 64 AGPR = 4 blocks/CU.
// Fused epilogues: proj writes V transposed; scores does exp + atomic
// rowsum; PV normalizes by 1/rowsum.
// ---------------------------------------------------------------------------

typedef __attribute__((ext_vector_type(8))) short bf16x8;
typedef __attribute__((ext_vector_type(4))) float f32x4;

__device__ __forceinline__ unsigned short f2bf(float f) {
  union { float f; uint32_t u; } x; x.f = f;
  uint32_t u = x.u;
  return (unsigned short)((u + 0x7fffu + ((u >> 16) & 1u)) >> 16);  // RNE
}

__device__ __forceinline__ void async_copy16(const void* g, void* l) {
  __builtin_amdgcn_global_load_lds(
      (const __attribute__((address_space(1))) void*)g,
      (__attribute__((address_space(3))) void*)l, 16, 0, 0);
}

// ---------------------------------------------------------------------------
// Merged fp32->bf16 convert for x, Wq, Wk, Wv; last block zeroes rowsum.
// ---------------------------------------------------------------------------
__global__ __launch_bounds__(256) void convert_all(
    const float* __restrict__ x, const float* __restrict__ Wq,
    const float* __restrict__ Wk, const float* __restrict__ Wv,
    unsigned short* __restrict__ xb, unsigned short* __restrict__ Wb,
    float* __restrict__ rowsum) {
  const long X4 = (long)8192 * 1024 / 4;
  const long W4 = (long)1024 * 1024 / 4;
  if (blockIdx.x == gridDim.x - 1) {
    float4* r = (float4*)rowsum;
#pragma unroll
    for (int t = 0; t < 8; ++t)
      r[threadIdx.x + t * 256] = float4{0.f, 0.f, 0.f, 0.f};
    return;
  }
  long i = (long)blockIdx.x * 256 + threadIdx.x;
  const float* src; unsigned short* dst; long off;
  if (i < X4)             { src = x;  dst = xb;                    off = i; }
  else if (i < X4 + W4)   { src = Wq; dst = Wb;                    off = i - X4; }
  else if (i < X4 + 2*W4) { src = Wk; dst = Wb + (long)1024*1024;  off = i - X4 - W4; }
  else                    { src = Wv; dst = Wb + (long)2048*1024;  off = i - X4 - 2*W4; }
  const float4 v = ((const float4*)src)[off];
  ushort4 o;
  o.x = f2bf(v.x); o.y = f2bf(v.y); o.z = f2bf(v.z); o.w = f2bf(v.w);
  ((ushort4*)dst)[off] = o;
}

// ---------------------------------------------------------------------------
// C[M,N] = op( scale * (A[M,K] x B[N,K]^T) + bias )
// MODE 0 (PROJ):   bf16 out; z<2 -> normal rows; z==2 -> write V transposed
// MODE 1 (SCORES): bf16 out = exp(scale*acc); atomicAdd per-row sums
// MODE 2 (PV):     fp32 out = acc * (1/rowsum[row])
// 256 threads = 4 waves, 128x128 tile, BK=64, 16x16x32 bf16 MFMA.
// Block swizzle: flat id -> 8x8 super-tiles (requires grid dims % 8 == 0).
// ---------------------------------------------------------------------------
template <int MODE>
__global__ __launch_bounds__(256, 4) void gemm_bt(
    const unsigned short* __restrict__ Ab, const unsigned short* __restrict__ Bb,
    unsigned short* __restrict__ Cb, float* __restrict__ Cf,
    unsigned short* __restrict__ VT,
    const float* __restrict__ bias0, const float* __restrict__ bias1,
    const float* __restrict__ bias2, float* __restrict__ rowsum,
    int K, int N, float scale, long sA, long sB, long sC) {
  __shared__ unsigned short As[128 * 64];
  __shared__ unsigned short Bs[128 * 64];

  const int z = blockIdx.z;
  const unsigned short* A  = Ab + (long)z * sA;
  const unsigned short* Bm = Bb + (long)z * sB;

  const int tid  = threadIdx.x;
  const int lane = tid & 63;
  const int wave = tid >> 6;
  const int l15  = lane & 15;
  const int quad = lane >> 4;
  const int wm = (wave >> 1) * 64;
  const int wn = (wave & 1) * 64;

  // --- 8x8 super-tile swizzle for L2 locality ---
  const int bxd  = gridDim.x;
  const int flat = blockIdx.y * bxd + blockIdx.x;
  const int st = flat >> 6;          // super-tile index (64 blocks each)
  const int inside = flat & 63;
  const int nstx = bxd >> 3;
  const int stx = st % nstx;
  const int sty = st / nstx;
  const int tile_m = (stx * 8 + (inside & 7)) * 128;
  const int tile_n = (sty * 8 + (inside >> 3)) * 128;

  // --- staging map: wave w covers rows [w*32, w*32+32), 4 instrs x 8 rows.
  // Lane L -> LDS slot L&7 of row strip+(L>>3); content = chunk (L&7)^(L>>3).
  const int rs8 = lane >> 3;
  const int kc  = (lane & 7) ^ rs8;
  const long lK = (long)K;
  const unsigned short* gA0 = A  + (long)(tile_m + wave * 32 + rs8) * lK + kc * 8;
  const unsigned short* gB0 = Bm + (long)(tile_n + wave * 32 + rs8) * lK + kc * 8;
  unsigned short* lA = &As[(wave * 32) * 64];
  unsigned short* lB = &Bs[(wave * 32) * 64];

  // --- fragment granule select: physical = (s*4+quad) ^ (row&7), row&7=l15&7
  const int g0 = (0 * 4 + quad) ^ (l15 & 7);
  const int g1 = (1 * 4 + quad) ^ (l15 & 7);

  f32x4 acc[4][4] = {};

  for (int k0 = 0; k0 < K; k0 += 64) {
    __syncthreads();  // previous-iter LDS readers done
#pragma unroll
    for (int t = 0; t < 4; ++t) {
      async_copy16(gA0 + (long)t * 8 * lK + k0, lA + t * 8 * 64);
      async_copy16(gB0 + (long)t * 8 * lK + k0, lB + t * 8 * 64);
    }
    __syncthreads();  // drain: LDS tile ready

#pragma unroll
    for (int s = 0; s < 2; ++s) {
      const int gs = s ? g1 : g0;
      bf16x8 af[4], bfr[4];
#pragma unroll
      for (int i = 0; i < 4; ++i)
        af[i] = *(const bf16x8*)&As[(wm + i * 16 + l15) * 64 + gs * 8];
#pragma unroll
      for (int j = 0; j < 4; ++j)
        bfr[j] = *(const bf16x8*)&Bs[(wn + j * 16 + l15) * 64 + gs * 8];
#pragma unroll
      for (int i = 0; i < 4; ++i)
#pragma unroll
        for (int j = 0; j < 4; ++j)
          acc[i][j] = __builtin_amdgcn_mfma_f32_16x16x32_bf16(af[i], bfr[j], acc[i][j], 0, 0, 0);
    }
  }

  // ------------------------- epilogue -------------------------
  // C/D layout: col = lane&15, row = quad*4 + reg (m89-verified)
  if (MODE == 0) {
    const float* bias = (z == 0) ? bias0 : (z == 1) ? bias1 : bias2;
    if (z == 2) {
      // write V transposed: VT[b][f][s], b = row>>11, s = row&2047
#pragma unroll
      for (int j = 0; j < 4; ++j) {
        const int col = tile_n + wn + j * 16 + l15;  // feature f
        const float bv = bias[col];
#pragma unroll
        for (int i = 0; i < 4; ++i) {
          const int row0 = tile_m + wm + i * 16 + quad * 4;  // token
          const int b = row0 >> 11;
          const int sx = row0 & 2047;
          ushort4 o;
          o.x = f2bf(acc[i][j][0] + bv);
          o.y = f2bf(acc[i][j][1] + bv);
          o.z = f2bf(acc[i][j][2] + bv);
          o.w = f2bf(acc[i][j][3] + bv);
          *(ushort4*)&VT[(long)b * 1024 * 2048 + (long)col * 2048 + sx] = o;
        }
      }
    } else {
      unsigned short* Cbz = Cb + (long)z * sC;
#pragma unroll
      for (int j = 0; j < 4; ++j) {
        const int col = tile_n + wn + j * 16 + l15;
        const float bv = bias[col];
#pragma unroll
        for (int i = 0; i < 4; ++i) {
          const int row0 = tile_m + wm + i * 16 + quad * 4;
#pragma unroll
          for (int r = 0; r < 4; ++r)
            Cbz[(long)(row0 + r) * N + col] = f2bf(acc[i][j][r] + bv);
        }
      }
    }
  } else if (MODE == 1) {
    // exp epilogue + row-sum atomics
    unsigned short* Cbz = Cb + (long)z * sC;
    float part[16];
#pragma unroll
    for (int t = 0; t < 16; ++t) part[t] = 0.0f;
#pragma unroll
    for (int j = 0; j < 4; ++j) {
      const int col = tile_n + wn + j * 16 + l15;
#pragma unroll
      for (int i = 0; i < 4; ++i) {
        const int row0 = tile_m + wm + i * 16 + quad * 4;
#pragma unroll
        for (int r = 0; r < 4; ++r) {
          const float e = __expf(acc[i][j][r] * scale);
          part[i * 4 + r] += e;
          Cbz[(long)(row0 + r) * N + col] = f2bf(e);
        }
      }
    }
    // reduce across the 16 lanes (l15) sharing each row
#pragma unroll
    for (int t = 0; t < 16; ++t)
#pragma unroll
      for (int o = 1; o < 16; o <<= 1)
        part[t] += __shfl_xor(part[t], o);
    if (l15 == 0) {
#pragma unroll
      for (int i = 0; i < 4; ++i) {
        const int row0 = tile_m + wm + i * 16 + quad * 4;
#pragma unroll
        for (int r = 0; r < 4; ++r)
          atomicAdd(&rowsum[z * 2048 + row0 + r], part[i * 4 + r]);
      }
    }
  } else {
    // PV: normalize by rowsum
    float* Cfz = Cf + (long)z * sC;
    float inv[16];
#pragma unroll
    for (int i = 0; i < 4; ++i) {
      const int row0 = tile_m + wm + i * 16 + quad * 4;
#pragma unroll
      for (int r = 0; r < 4; ++r)
        inv[i * 4 + r] = 1.0f / rowsum[z * 2048 + row0 + r];
    }
#pragma unroll
    for (int j = 0; j < 4; ++j) {
      const int col = tile_n + wn + j * 16 + l15;
#pragma unroll
      for (int i = 0; i < 4; ++i) {
        const int row0 = tile_m + wm + i * 16 + quad * 4;
#pragma unroll
        for (int r = 0; r < 4; ++r)
          Cfz[(long)(row0 + r) * N + col] = acc[i][j][r] * inv[i * 4 + r];
      }
    }
  }
}

// ---------------------------------------------------------------------------
extern "C" void kernel_launch(void* const* d_in, const int* in_sizes, int n_in,
                              void* d_out, int out_size, void* d_ws, size_t ws_size,
                              hipStream_t stream) {
  const float* x  = (const float*)d_in[0];
  const float* Wq = (const float*)d_in[1];
  const float* bq = (const float*)d_in[2];
  const float* Wk = (const float*)d_in[3];
  const float* bk = (const float*)d_in[4];
  const float* Wv = (const float*)d_in[5];
  const float* bv = (const float*)d_in[6];
  float* out = (float*)d_out;

  constexpr int Bt = 4, S = 2048, E = 1024;
  constexpr int M = Bt * S;  // 8192

  // ws layout (bf16): x_bf | W_bf(3) | Q | K | VT | P(exp scores) | rowsum(f32)
  unsigned short* xb = (unsigned short*)d_ws;
  unsigned short* Wb = xb + (size_t)M * E;
  unsigned short* Q  = Wb + (size_t)3 * E * E;
  unsigned short* Kb = Q + (size_t)M * E;
  unsigned short* VT = Kb + (size_t)M * E;
  unsigned short* P  = VT + (size_t)M * E;
  float* rowsum = (float*)(P + (size_t)Bt * S * S);

  // 1) converts + rowsum zeroing (one launch)
  const int conv_blocks = (M * E / 4 + 3 * (E * E / 4)) / 256 + 1;
  convert_all<<<dim3(conv_blocks), dim3(256), 0, stream>>>(x, Wq, Wk, Wv, xb, Wb, rowsum);

  // 2) projections: z in {Q,K,V}; y = x W^T + b; V written transposed
  gemm_bt<0><<<dim3(M / 128, E / 128, 3), dim3(256), 0, stream>>>(
      xb, Wb, Q, nullptr, VT, bq, bk, bv, nullptr, E, E, 1.0f,
      0L, (long)E * E, (long)M * E);

  // 3) P = exp(Q K^T / 32) (unnormalized) + row sums
  gemm_bt<1><<<dim3(S / 128, S / 128, Bt), dim3(256), 0, stream>>>(
      Q, Kb, P, nullptr, nullptr, nullptr, nullptr, nullptr, rowsum,
      E, S, 1.0f / 32.0f, (long)S * E, (long)S * E, (long)S * S);

  // 4) out = (P V) / rowsum   (fp32 out)
  gemm_bt<2><<<dim3(S / 128, E / 128, Bt), dim3(256), 0, stream>>>(
      P, VT, nullptr, out, nullptr, nullptr, nullptr, nullptr, rowsum,
      S, E, 1.0f, (long)S * S, (long)E * S, (long)S * E);
}